// Round 8
// baseline (195.904 us; speedup 1.0000x reference)
//
#include <hip/hip_runtime.h>
#include <stdint.h>

// ContrastiveLoss: B=8192, D=1024, n=2048, T=0.5
// K1: row-normalize f32 -> fp8 e4m3, PRE-SWIZZLED global layout
//     (chunk c of row r stored at position c^(r&7) within each 128B window)
// K2: 256x256 MFMA GEMM via MX-scaled fp8 (16x16x128, scale=1.0), BK=128,
//     LINEAR-source global_load_lds staging, relaxed 1-barrier/tile schedule,
//     XCD-chunked mapping; epilogue: exp-row-sum + triu sum
// K3: scalar finalize

#define BDIM 1024
#define BROWS 8192
#define NROWS 2048

#define BM 256
#define BN 256
#define BKB 128            // K-bytes per tile (fp8: 128 elems = 128 B/row)
#define NKT (BDIM / BKB)   // 8

typedef __attribute__((ext_vector_type(4))) int i32x4;
typedef __attribute__((ext_vector_type(8))) int i32x8;
typedef __attribute__((ext_vector_type(4))) float f32x4;

// float -> OCP e4m3fn, RNE, handles subnormals (|x| <= 1 for our data)
static __device__ __forceinline__ unsigned char f2e4m3(float x) {
  uint32_t u = __float_as_uint(x);
  uint32_t s = (u >> 24) & 0x80u;
  uint32_t a = u & 0x7fffffffu;
  if (a == 0) return (unsigned char)s;
  int e = (int)(a >> 23) - 127;
  uint32_t m = a & 0x7fffffu;
  if (e >= -6) {  // normal fp8 range (our |x|<=1 -> e<=0, no overflow)
    uint32_t keep = m >> 20;
    uint32_t rest = m & 0xfffffu;
    keep += (rest > 0x80000u) || (rest == 0x80000u && (keep & 1u));
    uint32_t v = ((uint32_t)(e + 7) << 3) + keep;
    return (unsigned char)(s | v);
  }
  if (e < -10) return (unsigned char)s;  // underflow to 0
  uint32_t full = 0x800000u | m;         // subnormal: e in [-10,-7]
  int sh = 14 - e;
  uint32_t keep = full >> sh;
  uint32_t rest = full & ((1u << sh) - 1u);
  uint32_t half = 1u << (sh - 1);
  keep += (rest > half) || (rest == half && (keep & 1u));
  return (unsigned char)(s | keep);
}

static __device__ __forceinline__ void gload_lds16(const unsigned char* g, unsigned char* l) {
  __builtin_amdgcn_global_load_lds(
      (const __attribute__((address_space(1))) uint32_t*)(const void*)g,
      (__attribute__((address_space(3))) uint32_t*)(void*)l,
      16, 0, 0);
}

static __device__ __forceinline__ uint32_t pk4(float4 v, float inv) {
  return (uint32_t)f2e4m3(v.x * inv) | ((uint32_t)f2e4m3(v.y * inv) << 8) |
         ((uint32_t)f2e4m3(v.z * inv) << 16) | ((uint32_t)f2e4m3(v.w * inv) << 24);
}

__global__ __launch_bounds__(256) void normalize_kernel(const float* __restrict__ emb,
                                                        unsigned char* __restrict__ zb,
                                                        float* __restrict__ denom,
                                                        float* __restrict__ sumsim) {
  const int w = threadIdx.x >> 6;
  const int lane = threadIdx.x & 63;
  const int row = blockIdx.x * 4 + w;
  const float4* src = reinterpret_cast<const float4*>(emb + (size_t)row * BDIM);
  // lane owns elements [lane*16, lane*16+16) = one 16B fp8 chunk
  float4 v[4];
  float ss = 0.f;
#pragma unroll
  for (int i = 0; i < 4; i++) {
    v[i] = src[lane * 4 + i];
    ss += v[i].x * v[i].x + v[i].y * v[i].y + v[i].z * v[i].z + v[i].w * v[i].w;
  }
#pragma unroll
  for (int m = 1; m < 64; m <<= 1) ss += __shfl_xor(ss, m);
  const float inv = rsqrtf(ss);
  uint4 o;
  o.x = pk4(v[0], inv);
  o.y = pk4(v[1], inv);
  o.z = pk4(v[2], inv);
  o.w = pk4(v[3], inv);
  // pre-swizzle: logical chunk (lane) stored at position (lane&56)|((lane&7)^(row&7))
  const int cp = (lane & 56) | ((lane & 7) ^ (row & 7));
  *reinterpret_cast<uint4*>(zb + (size_t)row * BDIM + cp * 16) = o;
  if (blockIdx.x < NROWS / 4 && lane == 0) denom[row] = 0.f;
  if (blockIdx.x == 0 && threadIdx.x == 0) sumsim[0] = 0.f;
}

// ---------------- GEMM ----------------
// zb is PRE-SWIZZLED: position p of row r holds logical chunk p^(r&7) (within
// each 128B window). Staging reads are strictly linear ((lane&7)*16), so LDS
// inherits the swizzled layout; fragment reads apply chunk^(row&7) as before.

__global__ __launch_bounds__(512, 2) void gemm_fused(const unsigned char* __restrict__ zb,
                                                     float* __restrict__ denom,
                                                     float* __restrict__ sumsim) {
  __shared__ unsigned char As[2][BM * BKB];
  __shared__ unsigned char Bs[2][BN * BKB];

  const int bx = blockIdx.x;           // 0..255
  const int xcd = bx & 7;
  const int idx = bx >> 3;             // 0..31
  const int jb = xcd * 4 + (idx & 3);  // 0..31
  const int ib = idx >> 2;             // 0..7
  const int i0 = ib * BM;
  const int j0 = jb * BN;

  const int t = threadIdx.x;
  const int lane = t & 63;
  const int w = t >> 6;
  const int WR = w >> 2;               // 0..1
  const int WC = w & 3;                // 0..3

  // staging: one gload = 64 lanes x 16B = 8 rows x 128B, LINEAR ascending
  const int rsh = lane >> 3;                 // row within 8-row group
  const int lin = (lane & 7) * 16;           // linear byte offset in row window
  const int aw = w * 8;

  // fragment reads
  const int q2 = lane >> 4;                  // 0..3 (k-chunk pair 2q2,2q2+1)
  const int rsub = lane & 15;
  const int rk = rsub & 7;                   // swizzle key (row mod 8)

  f32x4 acc[8][4] = {};
  i32x8 fB[4];

#define STG_A(buf, r0, kk) \
  gload_lds16(zb + (size_t)(i0 + (r0) + aw + rsh) * BDIM + (kk) + lin, &As[buf][((r0) + aw) * BKB])
#define STG_B(buf, r0, kk) \
  gload_lds16(zb + (size_t)(j0 + (r0) + aw + rsh) * BDIM + (kk) + lin, &Bs[buf][((r0) + aw) * BKB])

#define STAGE_TILE(buf, kk)                              \
  {                                                      \
    STG_A(buf, 0, kk);   STG_A(buf, 64, kk);             \
    STG_A(buf, 128, kk); STG_A(buf, 192, kk);            \
    STG_B(buf, 0, kk);   STG_B(buf, 64, kk);             \
    STG_B(buf, 128, kk); STG_B(buf, 192, kk);            \
  }

#define RD_FRAG(dst, base, row)                                                           \
  {                                                                                       \
    const i32x4 lo = *reinterpret_cast<const i32x4*>(&base[(size_t)(row) * BKB + (((2 * q2) ^ rk) * 16)]);      \
    const i32x4 hi = *reinterpret_cast<const i32x4*>(&base[(size_t)(row) * BKB + (((2 * q2 + 1) ^ rk) * 16)]);  \
    dst[0] = lo[0]; dst[1] = lo[1]; dst[2] = lo[2]; dst[3] = lo[3];                       \
    dst[4] = hi[0]; dst[5] = hi[1]; dst[6] = hi[2]; dst[7] = hi[3];                       \
  }

  // ---- prologue ----
  STAGE_TILE(0, 0);
  __syncthreads();

  int cur = 0;
  for (int kt = 0; kt < NKT; ++kt) {
    const int nb = cur ^ 1;
    if (kt + 1 < NKT) STAGE_TILE(nb, (kt + 1) * BKB);

#pragma unroll
    for (int nn = 0; nn < 4; nn++) {
      RD_FRAG(fB[nn], (&Bs[cur][0]), WC * 64 + nn * 16 + rsub);
    }

    __builtin_amdgcn_s_setprio(1);
#pragma unroll
    for (int mm = 0; mm < 8; mm++) {
      i32x8 a;
      RD_FRAG(a, (&As[cur][0]), WR * 128 + mm * 16 + rsub);
#pragma unroll
      for (int nn = 0; nn < 4; nn++) {
        acc[mm][nn] = __builtin_amdgcn_mfma_scale_f32_16x16x128_f8f6f4(
            a, fB[nn], acc[mm][nn], 0, 0, 0, 0x7f7f7f7f, 0, 0x7f7f7f7f);
      }
    }
    __builtin_amdgcn_s_setprio(0);

    __syncthreads();
    cur = nb;
  }

  // ---- epilogue: C/D layout col=lane&15, row=(lane>>4)*4+reg ----
  const int hi4 = lane >> 4;
  const int col_l = lane & 15;
  float ssim = 0.f;
#pragma unroll
  for (int m = 0; m < 8; m++) {
    const int gibase = i0 + WR * 128 + m * 16 + hi4 * 4;
#pragma unroll
    for (int r = 0; r < 4; r++) {
      const int gi = gibase + r;
      float dsum = 0.f;
#pragma unroll
      for (int n = 0; n < 4; n++) {
        const int gj = j0 + WC * 64 + n * 16 + col_l;
        const float s = acc[m][n][r] * 2.0f;
        const float e = __expf(s);
        if (gj != gi) dsum += e;               // denom excludes diagonal
        if (gj < NROWS && gi < gj) ssim += s;  // triu(rows[:, :n], k=1)
      }
      dsum += __shfl_xor(dsum, 1);
      dsum += __shfl_xor(dsum, 2);
      dsum += __shfl_xor(dsum, 4);
      dsum += __shfl_xor(dsum, 8);
      if (col_l == 0) atomicAdd(&denom[gi], dsum);
    }
  }
#pragma unroll
  for (int msk = 1; msk < 64; msk <<= 1) ssim += __shfl_xor(ssim, msk);
  if (lane == 0 && j0 < NROWS) atomicAdd(sumsim, ssim);
}

__global__ __launch_bounds__(1024) void finalize(const float* __restrict__ denom,
                                                 const float* __restrict__ sumsim,
                                                 float* __restrict__ out) {
  const int t = threadIdx.x;
  double s = 0.0;
#pragma unroll
  for (int i = t; i < NROWS; i += 1024) {
    s += (double)(NROWS - 1 - i) * log((double)denom[i]);
  }
#pragma unroll
  for (int m = 1; m < 64; m <<= 1) s += __shfl_xor(s, m);
  __shared__ double ws_[16];
  if ((t & 63) == 0) ws_[t >> 6] = s;
  __syncthreads();
  if (t == 0) {
    double tot = 0.0;
#pragma unroll
    for (int i = 0; i < 16; i++) tot += ws_[i];
    const double loss = tot - (double)sumsim[0];
    out[0] = (float)(-2.0 / (double)NROWS * (double)(NROWS - 1) * loss);
  }
}

extern "C" void kernel_launch(void* const* d_in, const int* in_sizes, int n_in,
                              void* d_out, int out_size, void* d_ws, size_t ws_size,
                              hipStream_t stream) {
  const float* emb = (const float*)d_in[0];
  unsigned char* zb = (unsigned char*)d_ws;
  float* denom = (float*)((char*)d_ws + (size_t)BROWS * BDIM);  // 8 MB fp8
  float* sumsim = denom + NROWS;
  float* out = (float*)d_out;

  normalize_kernel<<<BROWS / 4, 256, 0, stream>>>(emb, zb, denom, sumsim);
  gemm_fused<<<(BROWS / BN) * (NROWS / BM), 512, 0, stream>>>(zb, denom, sumsim);
  finalize<<<1, 1024, 0, stream>>>(denom, sumsim, out);
}

// Round 9
// 61.506 us; speedup vs baseline: 3.1851x; 3.1851x over previous
//
#include <hip/hip_runtime.h>
#include <stdint.h>

// ContrastiveLoss: B=8192, D=1024, n=2048, T=0.5
// K1: row-normalize f32 -> fp8 e4m3, PRE-SWIZZLED layout (chunk c of row r at
//     position c^(r&7) within each 128B window)
// K2: 128x128-tile MX-fp8 GEMM (16x16x128 scaled MFMA), single-buffer LDS 32KB,
//     4 waves, 4 blocks/CU, 2-barrier loop (m97-style), XCD-chunked mapping;
//     epilogue: exp-row-sum + triu sum
// K3: scalar finalize

#define BDIM 1024
#define BROWS 8192
#define NROWS 2048

#define BM 128
#define BN 128
#define BKB 128            // K-bytes per tile (fp8: 128 elems = 128 B/row)
#define NKT (BDIM / BKB)   // 8

typedef __attribute__((ext_vector_type(4))) int i32x4;
typedef __attribute__((ext_vector_type(8))) int i32x8;
typedef __attribute__((ext_vector_type(4))) float f32x4;

// float -> OCP e4m3fn, RNE, handles subnormals (|x| <= 1 for our data)
static __device__ __forceinline__ unsigned char f2e4m3(float x) {
  uint32_t u = __float_as_uint(x);
  uint32_t s = (u >> 24) & 0x80u;
  uint32_t a = u & 0x7fffffffu;
  if (a == 0) return (unsigned char)s;
  int e = (int)(a >> 23) - 127;
  uint32_t m = a & 0x7fffffu;
  if (e >= -6) {
    uint32_t keep = m >> 20;
    uint32_t rest = m & 0xfffffu;
    keep += (rest > 0x80000u) || (rest == 0x80000u && (keep & 1u));
    uint32_t v = ((uint32_t)(e + 7) << 3) + keep;
    return (unsigned char)(s | v);
  }
  if (e < -10) return (unsigned char)s;
  uint32_t full = 0x800000u | m;
  int sh = 14 - e;
  uint32_t keep = full >> sh;
  uint32_t rest = full & ((1u << sh) - 1u);
  uint32_t half = 1u << (sh - 1);
  keep += (rest > half) || (rest == half && (keep & 1u));
  return (unsigned char)(s | keep);
}

static __device__ __forceinline__ void gload_lds16(const unsigned char* g, unsigned char* l) {
  __builtin_amdgcn_global_load_lds(
      (const __attribute__((address_space(1))) uint32_t*)(const void*)g,
      (__attribute__((address_space(3))) uint32_t*)(void*)l,
      16, 0, 0);
}

static __device__ __forceinline__ uint32_t pk4(float4 v, float inv) {
  return (uint32_t)f2e4m3(v.x * inv) | ((uint32_t)f2e4m3(v.y * inv) << 8) |
         ((uint32_t)f2e4m3(v.z * inv) << 16) | ((uint32_t)f2e4m3(v.w * inv) << 24);
}

__global__ __launch_bounds__(256) void normalize_kernel(const float* __restrict__ emb,
                                                        unsigned char* __restrict__ zb,
                                                        float* __restrict__ denom,
                                                        float* __restrict__ sumsim) {
  const int w = threadIdx.x >> 6;
  const int lane = threadIdx.x & 63;
  const int row = blockIdx.x * 4 + w;
  const float4* src = reinterpret_cast<const float4*>(emb + (size_t)row * BDIM);
  float4 v[4];
  float ss = 0.f;
#pragma unroll
  for (int i = 0; i < 4; i++) {
    v[i] = src[lane * 4 + i];
    ss += v[i].x * v[i].x + v[i].y * v[i].y + v[i].z * v[i].z + v[i].w * v[i].w;
  }
#pragma unroll
  for (int m = 1; m < 64; m <<= 1) ss += __shfl_xor(ss, m);
  const float inv = rsqrtf(ss);
  uint4 o;
  o.x = pk4(v[0], inv);
  o.y = pk4(v[1], inv);
  o.z = pk4(v[2], inv);
  o.w = pk4(v[3], inv);
  // pre-swizzle: logical chunk (lane) stored at position (lane&56)|((lane&7)^(row&7))
  const int cp = (lane & 56) | ((lane & 7) ^ (row & 7));
  *reinterpret_cast<uint4*>(zb + (size_t)row * BDIM + cp * 16) = o;
  if (blockIdx.x < NROWS / 4 && lane == 0) denom[row] = 0.f;
  if (blockIdx.x == 0 && threadIdx.x == 0) sumsim[0] = 0.f;
}

// ---------------- GEMM ----------------
// zb PRE-SWIZZLED: position p of row r holds logical chunk p^(r&7).
// Staging reads strictly linear; LDS inherits swizzle; fragment reads apply
// chunk^(row&7). Single 32KB buffer, stage -> sync -> compute -> sync.

__global__ __launch_bounds__(256, 4) void gemm_fused(const unsigned char* __restrict__ zb,
                                                     float* __restrict__ denom,
                                                     float* __restrict__ sumsim) {
  __shared__ unsigned char As[BM * BKB];   // 16 KB
  __shared__ unsigned char Bs[BN * BKB];   // 16 KB

  // XCD-chunked: xcd owns 8 j-blocks x all 16 i-blocks (A 2MB + B 1MB < 4MB L2)
  const int bx = blockIdx.x;            // 0..1023
  const int xcd = bx & 7;
  const int idx = bx >> 3;              // 0..127
  const int jb = xcd * 8 + (idx & 7);   // 0..63
  const int ib = idx >> 3;              // 0..15
  const int i0 = ib * BM;               // [0,2048)
  const int j0 = jb * BN;               // [0,8192)

  const int t = threadIdx.x;
  const int lane = t & 63;
  const int w = t >> 6;                 // 0..3
  const int WR = w >> 1;                // 0..1
  const int WC = w & 1;                 // 0..1

  // staging: one gload = 64 lanes x 16B = 8 rows x 128B, linear ascending
  const int rsh = lane >> 3;
  const int lin = (lane & 7) * 16;
  const int aw = w * 32;                // wave stages A rows [w*32,+32), B same

  // fragment reads
  const int q2 = lane >> 4;             // 0..3 -> k-chunks {2q2, 2q2+1}
  const int rsub = lane & 15;
  const int rk = rsub & 7;

  f32x4 acc[4][4] = {};

#define STG_A(r0, kk) \
  gload_lds16(zb + (size_t)(i0 + (r0) + aw + rsh) * BDIM + (kk) + lin, &As[((r0) + aw) * BKB])
#define STG_B(r0, kk) \
  gload_lds16(zb + (size_t)(j0 + (r0) + aw + rsh) * BDIM + (kk) + lin, &Bs[((r0) + aw) * BKB])

#define RD_FRAG(dst, base, row)                                                                                  \
  {                                                                                                              \
    const i32x4 lo = *reinterpret_cast<const i32x4*>(&base[(size_t)(row) * BKB + (((2 * q2) ^ rk) * 16)]);       \
    const i32x4 hi = *reinterpret_cast<const i32x4*>(&base[(size_t)(row) * BKB + (((2 * q2 + 1) ^ rk) * 16)]);   \
    dst[0] = lo[0]; dst[1] = lo[1]; dst[2] = lo[2]; dst[3] = lo[3];                                              \
    dst[4] = hi[0]; dst[5] = hi[1]; dst[6] = hi[2]; dst[7] = hi[3];                                              \
  }

#pragma unroll 1
  for (int kt = 0; kt < NKT; ++kt) {
    const int kk = kt * BKB;
    // stage tile kt (A: rows aw..aw+31 via 4 gloads; B: same)
    STG_A(0, kk); STG_A(8, kk); STG_A(16, kk); STG_A(24, kk);
    STG_B(0, kk); STG_B(8, kk); STG_B(16, kk); STG_B(24, kk);
    __syncthreads();  // vmcnt(0) drained -> tile resident

    // compute: two nn-halves, fB pair held (16 regs) for register headroom
#pragma unroll
    for (int nh = 0; nh < 2; nh++) {
      i32x8 fB2[2];
      RD_FRAG(fB2[0], Bs, WC * 64 + (nh * 2 + 0) * 16 + rsub);
      RD_FRAG(fB2[1], Bs, WC * 64 + (nh * 2 + 1) * 16 + rsub);
      __builtin_amdgcn_s_setprio(1);
#pragma unroll
      for (int mm = 0; mm < 4; mm++) {
        i32x8 a;
        RD_FRAG(a, As, WR * 64 + mm * 16 + rsub);
        acc[mm][nh * 2 + 0] = __builtin_amdgcn_mfma_scale_f32_16x16x128_f8f6f4(
            a, fB2[0], acc[mm][nh * 2 + 0], 0, 0, 0, 0x7f7f7f7f, 0, 0x7f7f7f7f);
        acc[mm][nh * 2 + 1] = __builtin_amdgcn_mfma_scale_f32_16x16x128_f8f6f4(
            a, fB2[1], acc[mm][nh * 2 + 1], 0, 0, 0, 0x7f7f7f7f, 0, 0x7f7f7f7f);
      }
      __builtin_amdgcn_s_setprio(0);
    }
    __syncthreads();  // all reads done before next stage overwrites
  }

  // ---- epilogue: C/D layout col=lane&15, row=(lane>>4)*4+reg ----
  const int hi4 = lane >> 4;
  const int col_l = lane & 15;
  float ssim = 0.f;
#pragma unroll
  for (int m = 0; m < 4; m++) {
    const int gibase = i0 + WR * 64 + m * 16 + hi4 * 4;
#pragma unroll
    for (int r = 0; r < 4; r++) {
      const int gi = gibase + r;
      float dsum = 0.f;
#pragma unroll
      for (int n = 0; n < 4; n++) {
        const int gj = j0 + WC * 64 + n * 16 + col_l;
        const float s = acc[m][n][r] * 2.0f;
        const float e = __expf(s);
        if (gj != gi) dsum += e;               // denom excludes diagonal
        if (gj < NROWS && gi < gj) ssim += s;  // triu(rows[:, :n], k=1)
      }
      dsum += __shfl_xor(dsum, 1);
      dsum += __shfl_xor(dsum, 2);
      dsum += __shfl_xor(dsum, 4);
      dsum += __shfl_xor(dsum, 8);
      if (col_l == 0) atomicAdd(&denom[gi], dsum);
    }
  }
#pragma unroll
  for (int msk = 1; msk < 64; msk <<= 1) ssim += __shfl_xor(ssim, msk);
  if (lane == 0 && j0 < NROWS) atomicAdd(sumsim, ssim);
}

__global__ __launch_bounds__(1024) void finalize(const float* __restrict__ denom,
                                                 const float* __restrict__ sumsim,
                                                 float* __restrict__ out) {
  const int t = threadIdx.x;
  double s = 0.0;
#pragma unroll
  for (int i = t; i < NROWS; i += 1024) {
    s += (double)(NROWS - 1 - i) * log((double)denom[i]);
  }
#pragma unroll
  for (int m = 1; m < 64; m <<= 1) s += __shfl_xor(s, m);
  __shared__ double ws_[16];
  if ((t & 63) == 0) ws_[t >> 6] = s;
  __syncthreads();
  if (t == 0) {
    double tot = 0.0;
#pragma unroll
    for (int i = 0; i < 16; i++) tot += ws_[i];
    const double loss = tot - (double)sumsim[0];
    out[0] = (float)(-2.0 / (double)NROWS * (double)(NROWS - 1) * loss);
  }
}

extern "C" void kernel_launch(void* const* d_in, const int* in_sizes, int n_in,
                              void* d_out, int out_size, void* d_ws, size_t ws_size,
                              hipStream_t stream) {
  const float* emb = (const float*)d_in[0];
  unsigned char* zb = (unsigned char*)d_ws;
  float* denom = (float*)((char*)d_ws + (size_t)BROWS * BDIM);  // 8 MB fp8
  float* sumsim = denom + NROWS;
  float* out = (float*)d_out;

  normalize_kernel<<<BROWS / 4, 256, 0, stream>>>(emb, zb, denom, sumsim);
  gemm_fused<<<(NROWS / BM) * (BROWS / BN), 256, 0, stream>>>(zb, denom, sumsim);
  finalize<<<1, 1024, 0, stream>>>(denom, sumsim, out);
}